// Round 1
// baseline (2236.403 us; speedup 1.0000x reference)
//
#include <hip/hip_runtime.h>
#include <stdint.h>

typedef unsigned short u16;
typedef __attribute__((ext_vector_type(8))) short short8;
typedef __attribute__((ext_vector_type(4))) short s16x4;
typedef __attribute__((ext_vector_type(4))) float f32x4;

#define DEV __device__ __forceinline__

DEV u16 f2bf(float f) {
  union { float f; uint32_t u; } c; c.f = f;
  uint32_t u = c.u;
  uint32_t r = u + 0x7fffu + ((u >> 16) & 1u);  // RNE
  return (u16)(r >> 16);
}

DEV void g2l16(const void* g, void* l) {
  __builtin_amdgcn_global_load_lds((__attribute__((address_space(1))) void*)(g),
                                   (__attribute__((address_space(3))) void*)(l),
                                   16, 0, 0);
}

// ---------------- positional embedding (PositionEmbeddingSine) ----------------
__global__ void pos_kernel(float* __restrict__ pos) {
  int n = blockIdx.x;
  float yv = (float)((n >> 5) + 1) / (32.0f + 1e-6f) * 6.283185307179586f;
  float xv = (float)((n & 31) + 1) / (32.0f + 1e-6f) * 6.283185307179586f;
#pragma unroll
  for (int i = 0; i < 3; i++) {
    int d = threadIdx.x + i * 256;
    int dd = (d < 384) ? d : d - 384;
    float base = (d < 384) ? yv : xv;
    float ex = (float)(dd & ~1) / 384.0f;     // 2*floor(dd/2)/384
    float arg = base / powf(10000.0f, ex);
    pos[(size_t)n * 768 + d] = (dd & 1) ? cosf(arg) : sinf(arg);
  }
}

// ---------------- conv_w fp32 [768][256] -> bf16 (already N x K) ----------------
__global__ void convw_kernel(const float* __restrict__ src, u16* __restrict__ dst) {
  int i = blockIdx.x * 256 + threadIdx.x;
  dst[i] = f2bf(src[i]);
}

// ---------------- 32x32 tile transpose fp32 -> bf16 ----------------
DEV void tile_tr32(const float* __restrict__ src, u16* __restrict__ dst,
                   int R, int C, int tr, int tc, float (*tile)[33]) {
  int tx = threadIdx.x & 31, ty = threadIdx.x >> 5;  // 32 x 8
#pragma unroll
  for (int i = 0; i < 32; i += 8)
    tile[ty + i][tx] = src[(size_t)(tr * 32 + ty + i) * C + tc * 32 + tx];
  __syncthreads();
#pragma unroll
  for (int i = 0; i < 32; i += 8)
    dst[(size_t)(tc * 32 + ty + i) * R + tr * 32 + tx] = f2bf(tile[tx][ty + i]);
}

// all four weights of one layer, transposed to [N][K] bf16, one launch
__global__ void wconv_kernel(const float* __restrict__ qkv_w, const float* __restrict__ out_w,
                             const float* __restrict__ m1w, const float* __restrict__ m2w,
                             u16* __restrict__ wqkv, u16* __restrict__ wout,
                             u16* __restrict__ wm1, u16* __restrict__ wm2, int layer) {
  __shared__ float tile[32][33];
  int tid = blockIdx.x;
  if (tid < 1728) {                                   // qkv_w: [768][2304] -> [2304][768]
    tile_tr32(qkv_w + (size_t)layer * 768 * 2304, wqkv, 768, 2304, tid / 72, tid % 72, tile);
  } else if (tid < 2304) {                            // out_w: [768][768]
    int t2 = tid - 1728;
    tile_tr32(out_w + (size_t)layer * 768 * 768, wout, 768, 768, t2 / 24, t2 % 24, tile);
  } else if (tid < 4608) {                            // mlp_w1: [768][3072] -> [3072][768]
    int t3 = tid - 2304;
    tile_tr32(m1w + (size_t)layer * 768 * 3072, wm1, 768, 3072, t3 / 96, t3 % 96, tile);
  } else {                                            // mlp_w2: [3072][768] -> [768][3072]
    int t4 = tid - 4608;
    tile_tr32(m2w + (size_t)layer * 3072 * 768, wm2, 3072, 768, t4 / 24, t4 % 24, tile);
  }
}

// c_f [B][256][1024] fp32 -> aconv [B][1024][256] bf16
__global__ void cf_tr_kernel(const float* __restrict__ c_f, u16* __restrict__ aconv) {
  __shared__ float tile[32][33];
  int b = blockIdx.z;
  tile_tr32(c_f + (size_t)b * 256 * 1024, aconv + (size_t)b * 1024 * 256,
            256, 1024, blockIdx.y, blockIdx.x, tile);
}

// x [B][1024][768] fp32 -> out [B][768][1024] fp32
__global__ void out_tr_kernel(const float* __restrict__ x, float* __restrict__ out) {
  __shared__ float tile[32][33];
  int b = blockIdx.z;
  const float* src = x + (size_t)b * 1024 * 768;
  float* dst = out + (size_t)b * 768 * 1024;
  int tr = blockIdx.y, tc = blockIdx.x;  // tr over n (32 tiles), tc over d (24 tiles)
  int tx = threadIdx.x & 31, ty = threadIdx.x >> 5;
#pragma unroll
  for (int i = 0; i < 32; i += 8)
    tile[ty + i][tx] = src[(size_t)(tr * 32 + ty + i) * 768 + tc * 32 + tx];
  __syncthreads();
#pragma unroll
  for (int i = 0; i < 32; i += 8)
    dst[(size_t)(tc * 32 + ty + i) * 1024 + tr * 32 + tx] = tile[tx][ty + i];
}

// ---------------- LayerNorm: fp32 in -> bf16 out ----------------
__global__ __launch_bounds__(256) void ln_kernel(const float* __restrict__ x,
                                                 const float* __restrict__ w,
                                                 const float* __restrict__ bsh,
                                                 u16* __restrict__ y) {
  int row = blockIdx.x, t = threadIdx.x;
  const float* xr = x + (size_t)row * 768;
  float v[3], s = 0.f, sq = 0.f;
#pragma unroll
  for (int i = 0; i < 3; i++) { v[i] = xr[t + i * 256]; s += v[i]; sq += v[i] * v[i]; }
#pragma unroll
  for (int off = 32; off; off >>= 1) { s += __shfl_xor(s, off); sq += __shfl_xor(sq, off); }
  __shared__ float ss[4], ssq[4];
  if ((t & 63) == 0) { ss[t >> 6] = s; ssq[t >> 6] = sq; }
  __syncthreads();
  s = ss[0] + ss[1] + ss[2] + ss[3];
  sq = ssq[0] + ssq[1] + ssq[2] + ssq[3];
  float mean = s * (1.0f / 768.0f);
  float var = sq * (1.0f / 768.0f) - mean * mean;
  float rs = rsqrtf(var + 1e-5f);
#pragma unroll
  for (int i = 0; i < 3; i++) {
    int c = t + i * 256;
    y[(size_t)row * 768 + c] = f2bf((v[i] - mean) * rs * w[c] + bsh[c]);
  }
}

// ---------------- GEMM: C[M,N] = A[M,K](bf16) @ BT[N,K](bf16)^T, epilogues ----------------
// EPI_ATOMIC: split-K partial (blockIdx.z selects K-chunk), fp32 atomicAdd onto Cout
// (which must already hold the residual); bias added by the z==0 chunk only.
constexpr int EPI_BF16 = 0, EPI_BIAS_RES = 1, EPI_BIAS_GELU = 2, EPI_BIAS_POS = 3, EPI_ATOMIC = 4;

template <int EPI>
__global__ __launch_bounds__(256, 2) void gemm_bt(
    const u16* __restrict__ A, const u16* __restrict__ BT,
    const float* __restrict__ bias, const float* __restrict__ res,
    void* __restrict__ Cout, int M, int N, int K) {
  __shared__ __align__(16) u16 As[128 * 32];
  __shared__ __align__(16) u16 Bs[128 * 32];
  const int t = threadIdx.x;
  const int w = t >> 6, l = t & 63, lr = l & 15, quad = l >> 4;
  const int bm = blockIdx.y * 128, bn = blockIdx.x * 128;
  const int wm = (w & 1) * 64, wn = (w >> 1) * 64;
  f32x4 acc[4][4];
#pragma unroll
  for (int i = 0; i < 4; i++)
#pragma unroll
    for (int j = 0; j < 4; j++) acc[i][j] = (f32x4){0.f, 0.f, 0.f, 0.f};
  const int c0 = t, c1 = 256 + t;
  const size_t a0 = (size_t)(bm + (c0 >> 2)) * K + (c0 & 3) * 8;
  const size_t a1 = (size_t)(bm + (c1 >> 2)) * K + (c1 & 3) * 8;
  const size_t b0 = (size_t)(bn + (c0 >> 2)) * K + (c0 & 3) * 8;
  const size_t b1 = (size_t)(bn + (c1 >> 2)) * K + (c1 & 3) * 8;
  const int kc = K / (int)gridDim.z;                // K-chunk for split-K (kc==K if z==1)
  const int kBeg = (int)blockIdx.z * kc;
  for (int k0 = kBeg; k0 < kBeg + kc; k0 += 32) {
    g2l16(A + a0 + k0, As + c0 * 8);
    g2l16(A + a1 + k0, As + c1 * 8);
    g2l16(BT + b0 + k0, Bs + c0 * 8);
    g2l16(BT + b1 + k0, Bs + c1 * 8);
    __syncthreads();
    short8 af[4], bf[4];
#pragma unroll
    for (int mi = 0; mi < 4; mi++) af[mi] = *(const short8*)(As + (wm + mi * 16 + lr) * 32 + quad * 8);
#pragma unroll
    for (int nj = 0; nj < 4; nj++) bf[nj] = *(const short8*)(Bs + (wn + nj * 16 + lr) * 32 + quad * 8);
#pragma unroll
    for (int mi = 0; mi < 4; mi++)
#pragma unroll
      for (int nj = 0; nj < 4; nj++)
        acc[mi][nj] = __builtin_amdgcn_mfma_f32_16x16x32_bf16(af[mi], bf[nj], acc[mi][nj], 0, 0, 0);
    __syncthreads();
  }
#pragma unroll
  for (int mi = 0; mi < 4; mi++) {
    const int rowb = bm + wm + mi * 16 + quad * 4;
#pragma unroll
    for (int nj = 0; nj < 4; nj++) {
      const int gn = bn + wn + nj * 16 + lr;
#pragma unroll
      for (int r = 0; r < 4; r++) {
        const size_t idx = (size_t)(rowb + r) * N + gn;
        float v = acc[mi][nj][r];
        if constexpr (EPI == EPI_BF16) {
          ((u16*)Cout)[idx] = f2bf(v);
        } else if constexpr (EPI == EPI_BIAS_RES) {
          ((float*)Cout)[idx] = v + bias[gn] + res[idx];
        } else if constexpr (EPI == EPI_BIAS_GELU) {
          float xg = v + bias[gn];
          ((u16*)Cout)[idx] = f2bf(0.5f * xg * (1.0f + erff(xg * 0.70710678118f)));
        } else if constexpr (EPI == EPI_BIAS_POS) {  // conv epilogue, N==768
          ((float*)Cout)[idx] = v + bias[gn] + res[(size_t)((rowb + r) & 1023) * N + gn];
        } else {  // EPI_ATOMIC: split-K accumulate onto residual already in Cout
          float add = v + (blockIdx.z == 0 ? bias[gn] : 0.0f);
          atomicAdd((float*)Cout + idx, add);
        }
      }
    }
  }
}

// ---------------- V transpose: qkvb v-cols [4096][2304] -> vT [48][64][1024] ----------------
__global__ __launch_bounds__(256) void vtr_kernel(const u16* __restrict__ qkvb,
                                                  u16* __restrict__ vT) {
  __shared__ uint32_t tile[64][65];
  const int t = threadIdx.x;
  const int bh = blockIdx.y, b = bh / 12, h = bh % 12;
  const int tok0 = blockIdx.x * 64;
  {
    int trow = t >> 2, dc = (t & 3) * 16;
    const u16* src = qkvb + (size_t)(b * 1024 + tok0 + trow) * 2304 + 1536 + h * 64 + dc;
    short8 v0 = *(const short8*)src;
    short8 v1 = *(const short8*)(src + 8);
#pragma unroll
    for (int j = 0; j < 8; j++) {
      tile[trow][dc + j] = (uint32_t)(u16)v0[j];
      tile[trow][dc + 8 + j] = (uint32_t)(u16)v1[j];
    }
  }
  __syncthreads();
  {
    int d = t >> 2, tc = (t & 3) * 16;
    short8 o0, o1;
#pragma unroll
    for (int j = 0; j < 8; j++) {
      o0[j] = (short)(u16)tile[tc + j][d];
      o1[j] = (short)(u16)tile[tc + 8 + j][d];
    }
    u16* dst = vT + (size_t)(bh * 64 + d) * 1024 + tok0 + tc;
    *(short8*)dst = o0;
    *(short8*)(dst + 8) = o1;
  }
}

// ---------------- flash attention, S^T formulation ----------------
// Block = 128 threads (2 waves), each wave owns 32 q-rows (2 q-tiles of 16).
// K tile [ks][key][32] and V^T tile [ks][d][32] staged in LDS via g2l16.
// S^T = K @ Q^T (A=K, B=Q) -> C layout: col=q, row=key.  Unnormalized
// softmax (|s*scale| << 88), l reduced across quads once at the end.
// P^T round-trips per-wave LDS (packed b64 writes) into B-operand layout,
// O^T = V^T @ P^T.  Two barriers per 64-key iter protect the K/V tiles.
__global__ __launch_bounds__(128, 3) void attn_kernel(const u16* __restrict__ qkv,
                                                      const u16* __restrict__ vT,
                                                      u16* __restrict__ o) {
  __shared__ __align__(16) u16 Ks[2 * 64 * 32];   // [ks][key][32]
  __shared__ __align__(16) u16 Vs[2 * 64 * 32];   // [ks][d][32]
  __shared__ __align__(16) u16 Ps[2][32 * 72];    // per-wave P [qlocal][key], pad 72
  const int t = threadIdx.x;
  const int w = t >> 6, l = t & 63, lr = l & 15, quad = l >> 4;
  const int bh = blockIdx.y, b = bh / 12, h = bh % 12;
  const int qb = blockIdx.x * 64 + w * 32;        // 32 q-rows per wave

  // Q fragments (B-operand layout == [n=q][k=d], same lane layout as A)
  short8 aq[2][2];
#pragma unroll
  for (int qt = 0; qt < 2; qt++)
#pragma unroll
    for (int ks = 0; ks < 2; ks++)
      aq[qt][ks] = *(const short8*)(qkv + (size_t)(b * 1024 + qb + qt * 16 + lr) * 2304 +
                                    h * 64 + ks * 32 + quad * 8);

  const u16* kbase = qkv + (size_t)(b * 1024) * 2304 + 768 + h * 64;
  const u16* vbase = vT + (size_t)(bh * 64) * 1024;
  u16* Pw = Ps[w];

  f32x4 accO[4][2];   // [dj][qt]: O^T[d=dj*16+quad*4+r][q=qt*16+lr]
  float l_loc[2] = {0.f, 0.f};
#pragma unroll
  for (int dj = 0; dj < 4; dj++)
#pragma unroll
    for (int qt = 0; qt < 2; qt++) accO[dj][qt] = (f32x4){0.f, 0.f, 0.f, 0.f};

  for (int kb = 0; kb < 1024; kb += 64) {
    // ---- stage K and V^T tiles (lane-contiguous LDS, coalesced-ish global) ----
#pragma unroll
    for (int pass = 0; pass < 4; pass++) {
      int u = pass * 128 + t;                    // 16B unit index, 0..511
      int ks = u >> 8, row = (u >> 2) & 63, c4 = u & 3;
      g2l16(kbase + (size_t)(kb + row) * 2304 + ks * 32 + c4 * 8, Ks + (size_t)u * 8);
      g2l16(vbase + (size_t)row * 1024 + kb + ks * 32 + c4 * 8, Vs + (size_t)u * 8);
    }
    __syncthreads();

    // ---- S^T = K @ Q^T ----
    f32x4 s[4][2];   // [nj keytile][qt]
#pragma unroll
    for (int nj = 0; nj < 4; nj++)
#pragma unroll
      for (int qt = 0; qt < 2; qt++) s[nj][qt] = (f32x4){0.f, 0.f, 0.f, 0.f};
#pragma unroll
    for (int ks = 0; ks < 2; ks++)
#pragma unroll
      for (int nj = 0; nj < 4; nj++) {
        short8 ak = *(const short8*)(Ks + ks * 2048 + (nj * 16 + lr) * 32 + quad * 8);
#pragma unroll
        for (int qt = 0; qt < 2; qt++)
          s[nj][qt] = __builtin_amdgcn_mfma_f32_16x16x32_bf16(ak, aq[qt][ks], s[nj][qt], 0, 0, 0);
      }

    // ---- unnormalized softmax; P[qlocal][key] packed b64 writes ----
#pragma unroll
    for (int qt = 0; qt < 2; qt++) {
      const int rowoff = (qt * 16 + lr) * 72;
#pragma unroll
      for (int nj = 0; nj < 4; nj++) {
        s16x4 pk;
#pragma unroll
        for (int r = 0; r < 4; r++) {
          float p = exp2f(s[nj][qt][r] * 0.18033688011112042f);
          l_loc[qt] += p;
          pk[r] = (short)f2bf(p);
        }
        *(s16x4*)(Pw + rowoff + nj * 16 + quad * 4) = pk;
      }
    }

    // ---- O^T += V^T @ P^T ----
#pragma unroll
    for (int ks = 0; ks < 2; ks++) {
      short8 bp[2];
#pragma unroll
      for (int qt = 0; qt < 2; qt++)
        bp[qt] = *(const short8*)(Pw + (qt * 16 + lr) * 72 + ks * 32 + quad * 8);
#pragma unroll
      for (int dj = 0; dj < 4; dj++) {
        short8 av = *(const short8*)(Vs + ks * 2048 + (dj * 16 + lr) * 32 + quad * 8);
#pragma unroll
        for (int qt = 0; qt < 2; qt++)
          accO[dj][qt] = __builtin_amdgcn_mfma_f32_16x16x32_bf16(av, bp[qt], accO[dj][qt], 0, 0, 0);
      }
    }
    __syncthreads();
  }

  // l: reduce across the 4 quads (lanes lr, lr+16, lr+32, lr+48)
#pragma unroll
  for (int qt = 0; qt < 2; qt++) {
    l_loc[qt] += __shfl_xor(l_loc[qt], 16);
    l_loc[qt] += __shfl_xor(l_loc[qt], 32);
  }
  // write O: token = qb + qt*16 + lr, d = h*64 + dj*16 + quad*4 + r (b64 stores)
#pragma unroll
  for (int qt = 0; qt < 2; qt++) {
    float inv = 1.0f / l_loc[qt];
    size_t grow = (size_t)(b * 1024 + qb + qt * 16 + lr);
#pragma unroll
    for (int dj = 0; dj < 4; dj++) {
      s16x4 ov;
#pragma unroll
      for (int r = 0; r < 4; r++) ov[r] = (short)f2bf(accO[dj][qt][r] * inv);
      *(s16x4*)(o + grow * 768 + h * 64 + dj * 16 + quad * 4) = ov;
    }
  }
}

// ---------------- driver ----------------
extern "C" void kernel_launch(void* const* d_in, const int* in_sizes, int n_in,
                              void* d_out, int out_size, void* d_ws, size_t ws_size,
                              hipStream_t stream) {
  (void)in_sizes; (void)n_in; (void)out_size; (void)ws_size;
  const float* c_f    = (const float*)d_in[0];
  const float* conv_w = (const float*)d_in[1];
  const float* conv_b = (const float*)d_in[2];
  const float* ln1_w  = (const float*)d_in[3];
  const float* ln1_b  = (const float*)d_in[4];
  const float* qkv_w  = (const float*)d_in[5];
  const float* out_w  = (const float*)d_in[6];
  const float* out_b  = (const float*)d_in[7];
  const float* ln2_w  = (const float*)d_in[8];
  const float* ln2_b  = (const float*)d_in[9];
  const float* m1w    = (const float*)d_in[10];
  const float* m1b    = (const float*)d_in[11];
  const float* m2w    = (const float*)d_in[12];
  const float* m2b    = (const float*)d_in[13];
  float* out = (float*)d_out;

  char* p = (char*)d_ws;
  auto alloc = [&](size_t bytes) { char* q = p; p += (bytes + 255) & ~(size_t)255; return q; };
  float* pos  = (float*)alloc(1024ull * 768 * 4);
  float* x    = (float*)alloc(4096ull * 768 * 4);
  u16* y      = (u16*)alloc(4096ull * 768 * 2);
  u16* qkvb   = (u16*)alloc(4096ull * 2304 * 2);
  u16* ob     = (u16*)alloc(4096ull * 768 * 2);
  u16* hb     = (u16*)alloc(4096ull * 3072 * 2);
  u16* aconv  = (u16*)alloc(4096ull * 256 * 2);
  u16* convw  = (u16*)alloc(768ull * 256 * 2);
  u16* wqkv   = (u16*)alloc(2304ull * 768 * 2);
  u16* wout   = (u16*)alloc(768ull * 768 * 2);
  u16* wm1    = (u16*)alloc(3072ull * 768 * 2);
  u16* wm2    = (u16*)alloc(768ull * 3072 * 2);
  // vT [48][64][1024] bf16 (6.3 MB) aliases hb (25 MB): hb dead during attn.
  u16* vT = hb;

  pos_kernel<<<1024, 256, 0, stream>>>(pos);
  convw_kernel<<<768, 256, 0, stream>>>(conv_w, convw);
  cf_tr_kernel<<<dim3(32, 8, 4), 256, 0, stream>>>(c_f, aconv);
  gemm_bt<EPI_BIAS_POS><<<dim3(6, 32), 256, 0, stream>>>(aconv, convw, conv_b, pos, x, 4096, 768, 256);

  for (int lyr = 0; lyr < 8; lyr++) {
    wconv_kernel<<<6912, 256, 0, stream>>>(qkv_w, out_w, m1w, m2w, wqkv, wout, wm1, wm2, lyr);
    ln_kernel<<<4096, 256, 0, stream>>>(x, ln1_w + lyr * 768, ln1_b + lyr * 768, y);
    gemm_bt<EPI_BF16><<<dim3(18, 32), 256, 0, stream>>>(y, wqkv, nullptr, nullptr, qkvb, 4096, 2304, 768);
    vtr_kernel<<<dim3(16, 48), 256, 0, stream>>>(qkvb, vT);
    attn_kernel<<<dim3(16, 48), 128, 0, stream>>>(qkvb, vT, ob);
    // out-proj: split-K x4 (768 blocks -> ~3 resident blocks/CU), atomic accumulate onto x
    gemm_bt<EPI_ATOMIC><<<dim3(6, 32, 4), 256, 0, stream>>>(ob, wout, out_b + lyr * 768, nullptr, x, 4096, 768, 768);
    ln_kernel<<<4096, 256, 0, stream>>>(x, ln2_w + lyr * 768, ln2_b + lyr * 768, y);
    gemm_bt<EPI_BIAS_GELU><<<dim3(24, 32), 256, 0, stream>>>(y, wm1, m1b + lyr * 3072, nullptr, hb, 4096, 3072, 768);
    // mlp2: split-K x4 (768 blocks), atomic accumulate onto x
    gemm_bt<EPI_ATOMIC><<<dim3(6, 32, 4), 256, 0, stream>>>(hb, wm2, m2b + lyr * 768, nullptr, x, 4096, 768, 3072);
  }
  out_tr_kernel<<<dim3(24, 32, 4), 256, 0, stream>>>(x, out);
}

// Round 2
// 1803.441 us; speedup vs baseline: 1.2401x; 1.2401x over previous
//
#include <hip/hip_runtime.h>
#include <stdint.h>

typedef unsigned short u16;
typedef __attribute__((ext_vector_type(8))) short short8;
typedef __attribute__((ext_vector_type(4))) short s16x4;
typedef __attribute__((ext_vector_type(4))) float f32x4;

struct P4 { float* p[4]; };

#define DEV __device__ __forceinline__

DEV u16 f2bf(float f) {
  union { float f; uint32_t u; } c; c.f = f;
  uint32_t u = c.u;
  uint32_t r = u + 0x7fffu + ((u >> 16) & 1u);  // RNE
  return (u16)(r >> 16);
}

DEV void g2l16(const void* g, void* l) {
  __builtin_amdgcn_global_load_lds((__attribute__((address_space(1))) void*)(g),
                                   (__attribute__((address_space(3))) void*)(l),
                                   16, 0, 0);
}

// ---------------- positional embedding (PositionEmbeddingSine) ----------------
__global__ void pos_kernel(float* __restrict__ pos) {
  int n = blockIdx.x;
  float yv = (float)((n >> 5) + 1) / (32.0f + 1e-6f) * 6.283185307179586f;
  float xv = (float)((n & 31) + 1) / (32.0f + 1e-6f) * 6.283185307179586f;
#pragma unroll
  for (int i = 0; i < 3; i++) {
    int d = threadIdx.x + i * 256;
    int dd = (d < 384) ? d : d - 384;
    float base = (d < 384) ? yv : xv;
    float ex = (float)(dd & ~1) / 384.0f;     // 2*floor(dd/2)/384
    float arg = base / powf(10000.0f, ex);
    pos[(size_t)n * 768 + d] = (dd & 1) ? cosf(arg) : sinf(arg);
  }
}

// ---------------- conv_w fp32 [768][256] -> bf16 (already N x K) ----------------
__global__ void convw_kernel(const float* __restrict__ src, u16* __restrict__ dst) {
  int i = blockIdx.x * 256 + threadIdx.x;
  dst[i] = f2bf(src[i]);
}

// ---------------- 32x32 tile transpose fp32 -> bf16 ----------------
DEV void tile_tr32(const float* __restrict__ src, u16* __restrict__ dst,
                   int R, int C, int tr, int tc, float (*tile)[33]) {
  int tx = threadIdx.x & 31, ty = threadIdx.x >> 5;  // 32 x 8
#pragma unroll
  for (int i = 0; i < 32; i += 8)
    tile[ty + i][tx] = src[(size_t)(tr * 32 + ty + i) * C + tc * 32 + tx];
  __syncthreads();
#pragma unroll
  for (int i = 0; i < 32; i += 8)
    dst[(size_t)(tc * 32 + ty + i) * R + tr * 32 + tx] = f2bf(tile[tx][ty + i]);
}

// all four weights of one layer, transposed to [N][K] bf16, one launch
__global__ void wconv_kernel(const float* __restrict__ qkv_w, const float* __restrict__ out_w,
                             const float* __restrict__ m1w, const float* __restrict__ m2w,
                             u16* __restrict__ wqkv, u16* __restrict__ wout,
                             u16* __restrict__ wm1, u16* __restrict__ wm2, int layer) {
  __shared__ float tile[32][33];
  int tid = blockIdx.x;
  if (tid < 1728) {                                   // qkv_w: [768][2304] -> [2304][768]
    tile_tr32(qkv_w + (size_t)layer * 768 * 2304, wqkv, 768, 2304, tid / 72, tid % 72, tile);
  } else if (tid < 2304) {                            // out_w: [768][768]
    int t2 = tid - 1728;
    tile_tr32(out_w + (size_t)layer * 768 * 768, wout, 768, 768, t2 / 24, t2 % 24, tile);
  } else if (tid < 4608) {                            // mlp_w1: [768][3072] -> [3072][768]
    int t3 = tid - 2304;
    tile_tr32(m1w + (size_t)layer * 768 * 3072, wm1, 768, 3072, t3 / 96, t3 % 96, tile);
  } else {                                            // mlp_w2: [3072][768] -> [768][3072]
    int t4 = tid - 4608;
    tile_tr32(m2w + (size_t)layer * 3072 * 768, wm2, 3072, 768, t4 / 24, t4 % 24, tile);
  }
}

// c_f [B][256][1024] fp32 -> aconv [B][1024][256] bf16
__global__ void cf_tr_kernel(const float* __restrict__ c_f, u16* __restrict__ aconv) {
  __shared__ float tile[32][33];
  int b = blockIdx.z;
  tile_tr32(c_f + (size_t)b * 256 * 1024, aconv + (size_t)b * 1024 * 256,
            256, 1024, blockIdx.y, blockIdx.x, tile);
}

// x [B][1024][768] fp32 -> out [B][768][1024] fp32
__global__ void out_tr_kernel(const float* __restrict__ x, float* __restrict__ out) {
  __shared__ float tile[32][33];
  int b = blockIdx.z;
  const float* src = x + (size_t)b * 1024 * 768;
  float* dst = out + (size_t)b * 768 * 1024;
  int tr = blockIdx.y, tc = blockIdx.x;  // tr over n (32 tiles), tc over d (24 tiles)
  int tx = threadIdx.x & 31, ty = threadIdx.x >> 5;
#pragma unroll
  for (int i = 0; i < 32; i += 8)
    tile[ty + i][tx] = src[(size_t)(tr * 32 + ty + i) * 768 + tc * 32 + tx];
  __syncthreads();
#pragma unroll
  for (int i = 0; i < 32; i += 8)
    dst[(size_t)(tc * 32 + ty + i) * 1024 + tr * 32 + tx] = tile[tx][ty + i];
}

// ---------------- LayerNorm: fp32 in -> bf16 out ----------------
__global__ __launch_bounds__(256) void ln_kernel(const float* __restrict__ x,
                                                 const float* __restrict__ w,
                                                 const float* __restrict__ bsh,
                                                 u16* __restrict__ y) {
  int row = blockIdx.x, t = threadIdx.x;
  const float* xr = x + (size_t)row * 768;
  float v[3], s = 0.f, sq = 0.f;
#pragma unroll
  for (int i = 0; i < 3; i++) { v[i] = xr[t + i * 256]; s += v[i]; sq += v[i] * v[i]; }
#pragma unroll
  for (int off = 32; off; off >>= 1) { s += __shfl_xor(s, off); sq += __shfl_xor(sq, off); }
  __shared__ float ss[4], ssq[4];
  if ((t & 63) == 0) { ss[t >> 6] = s; ssq[t >> 6] = sq; }
  __syncthreads();
  s = ss[0] + ss[1] + ss[2] + ss[3];
  sq = ssq[0] + ssq[1] + ssq[2] + ssq[3];
  float mean = s * (1.0f / 768.0f);
  float var = sq * (1.0f / 768.0f) - mean * mean;
  float rs = rsqrtf(var + 1e-5f);
#pragma unroll
  for (int i = 0; i < 3; i++) {
    int c = t + i * 256;
    y[(size_t)row * 768 + c] = f2bf((v[i] - mean) * rs * w[c] + bsh[c]);
  }
}

// ---------------- fused split-K reduce (+ bias + residual) and LayerNorm ----------------
// x_new = sum_{s<S} parts.p[s] + bias + x_old; writes x_new (fp32) and, if DO_LN,
// y = LN(x_new) (bf16) using w/bsh.
template <int S, bool DO_LN>
__global__ __launch_bounds__(256) void redln_kernel(P4 parts, const float* __restrict__ xin,
                                                    const float* __restrict__ bias,
                                                    const float* __restrict__ w,
                                                    const float* __restrict__ bsh,
                                                    float* __restrict__ xout,
                                                    u16* __restrict__ y) {
  int row = blockIdx.x, t = threadIdx.x;
  size_t base = (size_t)row * 768;
  float v[3], s = 0.f, sq = 0.f;
#pragma unroll
  for (int i = 0; i < 3; i++) {
    int c = t + i * 256;
    float acc = xin[base + c] + bias[c];
#pragma unroll
    for (int j = 0; j < S; j++) acc += parts.p[j][base + c];
    v[i] = acc;
    xout[base + c] = acc;
    s += acc; sq += acc * acc;
  }
  if constexpr (DO_LN) {
#pragma unroll
    for (int off = 32; off; off >>= 1) { s += __shfl_xor(s, off); sq += __shfl_xor(sq, off); }
    __shared__ float ss[4], ssq[4];
    if ((t & 63) == 0) { ss[t >> 6] = s; ssq[t >> 6] = sq; }
    __syncthreads();
    s = ss[0] + ss[1] + ss[2] + ss[3];
    sq = ssq[0] + ssq[1] + ssq[2] + ssq[3];
    float mean = s * (1.0f / 768.0f);
    float var = sq * (1.0f / 768.0f) - mean * mean;
    float rs = rsqrtf(var + 1e-5f);
#pragma unroll
    for (int i = 0; i < 3; i++) {
      int c = t + i * 256;
      y[base + c] = f2bf((v[i] - mean) * rs * w[c] + bsh[c]);
    }
  }
}

// ---------------- GEMM: C[M,N] = A[M,K](bf16) @ BT[N,K](bf16)^T, epilogues ----------------
// EPI_PART: split-K; chunk z writes fp32 partial (no bias) to parts.p[z].
constexpr int EPI_BF16 = 0, EPI_BIAS_RES = 1, EPI_BIAS_GELU = 2, EPI_BIAS_POS = 3, EPI_PART = 4;

template <int EPI>
__global__ __launch_bounds__(256, 2) void gemm_bt(
    const u16* __restrict__ A, const u16* __restrict__ BT,
    const float* __restrict__ bias, const float* __restrict__ res,
    void* __restrict__ Cout, int M, int N, int K, P4 parts) {
  __shared__ __align__(16) u16 As[128 * 32];
  __shared__ __align__(16) u16 Bs[128 * 32];
  const int t = threadIdx.x;
  const int w = t >> 6, l = t & 63, lr = l & 15, quad = l >> 4;
  const int bm = blockIdx.y * 128, bn = blockIdx.x * 128;
  const int wm = (w & 1) * 64, wn = (w >> 1) * 64;
  f32x4 acc[4][4];
#pragma unroll
  for (int i = 0; i < 4; i++)
#pragma unroll
    for (int j = 0; j < 4; j++) acc[i][j] = (f32x4){0.f, 0.f, 0.f, 0.f};
  const int c0 = t, c1 = 256 + t;
  const size_t a0 = (size_t)(bm + (c0 >> 2)) * K + (c0 & 3) * 8;
  const size_t a1 = (size_t)(bm + (c1 >> 2)) * K + (c1 & 3) * 8;
  const size_t b0 = (size_t)(bn + (c0 >> 2)) * K + (c0 & 3) * 8;
  const size_t b1 = (size_t)(bn + (c1 >> 2)) * K + (c1 & 3) * 8;
  const int kc = K / (int)gridDim.z;                // K-chunk for split-K (kc==K if z==1)
  const int kBeg = (int)blockIdx.z * kc;
  for (int k0 = kBeg; k0 < kBeg + kc; k0 += 32) {
    g2l16(A + a0 + k0, As + c0 * 8);
    g2l16(A + a1 + k0, As + c1 * 8);
    g2l16(BT + b0 + k0, Bs + c0 * 8);
    g2l16(BT + b1 + k0, Bs + c1 * 8);
    __syncthreads();
    short8 af[4], bf[4];
#pragma unroll
    for (int mi = 0; mi < 4; mi++) af[mi] = *(const short8*)(As + (wm + mi * 16 + lr) * 32 + quad * 8);
#pragma unroll
    for (int nj = 0; nj < 4; nj++) bf[nj] = *(const short8*)(Bs + (wn + nj * 16 + lr) * 32 + quad * 8);
#pragma unroll
    for (int mi = 0; mi < 4; mi++)
#pragma unroll
      for (int nj = 0; nj < 4; nj++)
        acc[mi][nj] = __builtin_amdgcn_mfma_f32_16x16x32_bf16(af[mi], bf[nj], acc[mi][nj], 0, 0, 0);
    __syncthreads();
  }
  float* Pc = (EPI == EPI_PART) ? parts.p[blockIdx.z] : nullptr;
#pragma unroll
  for (int mi = 0; mi < 4; mi++) {
    const int rowb = bm + wm + mi * 16 + quad * 4;
#pragma unroll
    for (int nj = 0; nj < 4; nj++) {
      const int gn = bn + wn + nj * 16 + lr;
#pragma unroll
      for (int r = 0; r < 4; r++) {
        const size_t idx = (size_t)(rowb + r) * N + gn;
        float v = acc[mi][nj][r];
        if constexpr (EPI == EPI_BF16) {
          ((u16*)Cout)[idx] = f2bf(v);
        } else if constexpr (EPI == EPI_BIAS_RES) {
          ((float*)Cout)[idx] = v + bias[gn] + res[idx];
        } else if constexpr (EPI == EPI_BIAS_GELU) {
          float xg = v + bias[gn];
          ((u16*)Cout)[idx] = f2bf(0.5f * xg * (1.0f + erff(xg * 0.70710678118f)));
        } else if constexpr (EPI == EPI_BIAS_POS) {  // conv epilogue, N==768
          ((float*)Cout)[idx] = v + bias[gn] + res[(size_t)((rowb + r) & 1023) * N + gn];
        } else {  // EPI_PART: fp32 partial, combined later by redln_kernel
          Pc[idx] = v;
        }
      }
    }
  }
}

// ---------------- V transpose: qkvb v-cols [4096][2304] -> vT [48][64][1024] ----------------
__global__ __launch_bounds__(256) void vtr_kernel(const u16* __restrict__ qkvb,
                                                  u16* __restrict__ vT) {
  __shared__ uint32_t tile[64][65];
  const int t = threadIdx.x;
  const int bh = blockIdx.y, b = bh / 12, h = bh % 12;
  const int tok0 = blockIdx.x * 64;
  {
    int trow = t >> 2, dc = (t & 3) * 16;
    const u16* src = qkvb + (size_t)(b * 1024 + tok0 + trow) * 2304 + 1536 + h * 64 + dc;
    short8 v0 = *(const short8*)src;
    short8 v1 = *(const short8*)(src + 8);
#pragma unroll
    for (int j = 0; j < 8; j++) {
      tile[trow][dc + j] = (uint32_t)(u16)v0[j];
      tile[trow][dc + 8 + j] = (uint32_t)(u16)v1[j];
    }
  }
  __syncthreads();
  {
    int d = t >> 2, tc = (t & 3) * 16;
    short8 o0, o1;
#pragma unroll
    for (int j = 0; j < 8; j++) {
      o0[j] = (short)(u16)tile[tc + j][d];
      o1[j] = (short)(u16)tile[tc + 8 + j][d];
    }
    u16* dst = vT + (size_t)(bh * 64 + d) * 1024 + tok0 + tc;
    *(short8*)dst = o0;
    *(short8*)(dst + 8) = o1;
  }
}

// ---------------- flash attention, S^T formulation ----------------
// Block = 128 threads (2 waves), each wave owns 32 q-rows (2 q-tiles of 16).
// K tile [ks][key][32] and V^T tile [ks][d][32] staged in LDS via g2l16.
// S^T = K @ Q^T (A=K, B=Q) -> C layout: col=q, row=key.  Unnormalized
// softmax (|s*scale| << 88), l reduced across quads once at the end.
// P^T round-trips per-wave LDS (packed b64 writes) into B-operand layout,
// O^T = V^T @ P^T.  Two barriers per 64-key iter protect the K/V tiles.
__global__ __launch_bounds__(128, 3) void attn_kernel(const u16* __restrict__ qkv,
                                                      const u16* __restrict__ vT,
                                                      u16* __restrict__ o) {
  __shared__ __align__(16) u16 Ks[2 * 64 * 32];   // [ks][key][32]
  __shared__ __align__(16) u16 Vs[2 * 64 * 32];   // [ks][d][32]
  __shared__ __align__(16) u16 Ps[2][32 * 72];    // per-wave P [qlocal][key], pad 72
  const int t = threadIdx.x;
  const int w = t >> 6, l = t & 63, lr = l & 15, quad = l >> 4;
  const int bh = blockIdx.y, b = bh / 12, h = bh % 12;
  const int qb = blockIdx.x * 64 + w * 32;        // 32 q-rows per wave

  // Q fragments (B-operand layout == [n=q][k=d], same lane layout as A)
  short8 aq[2][2];
#pragma unroll
  for (int qt = 0; qt < 2; qt++)
#pragma unroll
    for (int ks = 0; ks < 2; ks++)
      aq[qt][ks] = *(const short8*)(qkv + (size_t)(b * 1024 + qb + qt * 16 + lr) * 2304 +
                                    h * 64 + ks * 32 + quad * 8);

  const u16* kbase = qkv + (size_t)(b * 1024) * 2304 + 768 + h * 64;
  const u16* vbase = vT + (size_t)(bh * 64) * 1024;
  u16* Pw = Ps[w];

  f32x4 accO[4][2];   // [dj][qt]: O^T[d=dj*16+quad*4+r][q=qt*16+lr]
  float l_loc[2] = {0.f, 0.f};
#pragma unroll
  for (int dj = 0; dj < 4; dj++)
#pragma unroll
    for (int qt = 0; qt < 2; qt++) accO[dj][qt] = (f32x4){0.f, 0.f, 0.f, 0.f};

  for (int kb = 0; kb < 1024; kb += 64) {
    // ---- stage K and V^T tiles (lane-contiguous LDS, coalesced-ish global) ----
#pragma unroll
    for (int pass = 0; pass < 4; pass++) {
      int u = pass * 128 + t;                    // 16B unit index, 0..511
      int ks = u >> 8, row = (u >> 2) & 63, c4 = u & 3;
      g2l16(kbase + (size_t)(kb + row) * 2304 + ks * 32 + c4 * 8, Ks + (size_t)u * 8);
      g2l16(vbase + (size_t)row * 1024 + kb + ks * 32 + c4 * 8, Vs + (size_t)u * 8);
    }
    __syncthreads();

    // ---- S^T = K @ Q^T ----
    f32x4 s[4][2];   // [nj keytile][qt]
#pragma unroll
    for (int nj = 0; nj < 4; nj++)
#pragma unroll
      for (int qt = 0; qt < 2; qt++) s[nj][qt] = (f32x4){0.f, 0.f, 0.f, 0.f};
#pragma unroll
    for (int ks = 0; ks < 2; ks++)
#pragma unroll
      for (int nj = 0; nj < 4; nj++) {
        short8 ak = *(const short8*)(Ks + ks * 2048 + (nj * 16 + lr) * 32 + quad * 8);
#pragma unroll
        for (int qt = 0; qt < 2; qt++)
          s[nj][qt] = __builtin_amdgcn_mfma_f32_16x16x32_bf16(ak, aq[qt][ks], s[nj][qt], 0, 0, 0);
      }

    // ---- unnormalized softmax; P[qlocal][key] packed b64 writes ----
#pragma unroll
    for (int qt = 0; qt < 2; qt++) {
      const int rowoff = (qt * 16 + lr) * 72;
#pragma unroll
      for (int nj = 0; nj < 4; nj++) {
        s16x4 pk;
#pragma unroll
        for (int r = 0; r < 4; r++) {
          float p = exp2f(s[nj][qt][r] * 0.18033688011112042f);
          l_loc[qt] += p;
          pk[r] = (short)f2bf(p);
        }
        *(s16x4*)(Pw + rowoff + nj * 16 + quad * 4) = pk;
      }
    }

    // ---- O^T += V^T @ P^T ----
#pragma unroll
    for (int ks = 0; ks < 2; ks++) {
      short8 bp[2];
#pragma unroll
      for (int qt = 0; qt < 2; qt++)
        bp[qt] = *(const short8*)(Pw + (qt * 16 + lr) * 72 + ks * 32 + quad * 8);
#pragma unroll
      for (int dj = 0; dj < 4; dj++) {
        short8 av = *(const short8*)(Vs + ks * 2048 + (dj * 16 + lr) * 32 + quad * 8);
#pragma unroll
        for (int qt = 0; qt < 2; qt++)
          accO[dj][qt] = __builtin_amdgcn_mfma_f32_16x16x32_bf16(av, bp[qt], accO[dj][qt], 0, 0, 0);
      }
    }
    __syncthreads();
  }

  // l: reduce across the 4 quads (lanes lr, lr+16, lr+32, lr+48)
#pragma unroll
  for (int qt = 0; qt < 2; qt++) {
    l_loc[qt] += __shfl_xor(l_loc[qt], 16);
    l_loc[qt] += __shfl_xor(l_loc[qt], 32);
  }
  // write O: token = qb + qt*16 + lr, d = h*64 + dj*16 + quad*4 + r (b64 stores)
#pragma unroll
  for (int qt = 0; qt < 2; qt++) {
    float inv = 1.0f / l_loc[qt];
    size_t grow = (size_t)(b * 1024 + qb + qt * 16 + lr);
#pragma unroll
    for (int dj = 0; dj < 4; dj++) {
      s16x4 ov;
#pragma unroll
      for (int r = 0; r < 4; r++) ov[r] = (short)f2bf(accO[dj][qt][r] * inv);
      *(s16x4*)(o + grow * 768 + h * 64 + dj * 16 + quad * 4) = ov;
    }
  }
}

// ---------------- driver ----------------
extern "C" void kernel_launch(void* const* d_in, const int* in_sizes, int n_in,
                              void* d_out, int out_size, void* d_ws, size_t ws_size,
                              hipStream_t stream) {
  (void)in_sizes; (void)n_in; (void)out_size;
  const float* c_f    = (const float*)d_in[0];
  const float* conv_w = (const float*)d_in[1];
  const float* conv_b = (const float*)d_in[2];
  const float* ln1_w  = (const float*)d_in[3];
  const float* ln1_b  = (const float*)d_in[4];
  const float* qkv_w  = (const float*)d_in[5];
  const float* out_w  = (const float*)d_in[6];
  const float* out_b  = (const float*)d_in[7];
  const float* ln2_w  = (const float*)d_in[8];
  const float* ln2_b  = (const float*)d_in[9];
  const float* m1w    = (const float*)d_in[10];
  const float* m1b    = (const float*)d_in[11];
  const float* m2w    = (const float*)d_in[12];
  const float* m2b    = (const float*)d_in[13];
  float* out = (float*)d_out;

  char* p = (char*)d_ws;
  auto alloc = [&](size_t bytes) { char* q = p; p += (bytes + 255) & ~(size_t)255; return q; };
  float* pos  = (float*)alloc(1024ull * 768 * 4);
  float* x    = (float*)alloc(4096ull * 768 * 4);
  u16* y      = (u16*)alloc(4096ull * 768 * 2);
  u16* qkvb   = (u16*)alloc(4096ull * 2304 * 2);
  u16* ob     = (u16*)alloc(4096ull * 768 * 2);
  u16* hb     = (u16*)alloc(4096ull * 3072 * 2);
  u16* aconv  = (u16*)alloc(4096ull * 256 * 2);
  u16* convw  = (u16*)alloc(768ull * 256 * 2);
  u16* wqkv   = (u16*)alloc(2304ull * 768 * 2);
  u16* wout   = (u16*)alloc(768ull * 768 * 2);
  u16* wm1    = (u16*)alloc(3072ull * 768 * 2);
  u16* wm2    = (u16*)alloc(768ull * 3072 * 2);
  // vT [48][64][1024] bf16 (6.3 MB) aliases hb (25 MB): hb dead during attn.
  u16* vT = hb;

  // ---- split-K partial buffers for mlp2 (each 4096*768*4 = 12.58 MB) ----
  // Live only between the mlp2 split-GEMM (end of layer l) and the fused
  // redln at the top of layer l+1.  During that window qkvb and ob are dead
  // (attn/out-proj done), d_out is scratch, y must stay untouched (redln
  // writes y).  p0 = qkvb, p1 = qkvb+12.58MB (tail of qkvb + ob, contiguous).
  const size_t PSZ = 4096ull * 768 * 4;
  P4 parts{};
  parts.p[0] = (float*)qkvb;
  parts.p[1] = (float*)((char*)qkvb + PSZ);
  int SPLIT = 2;
  if ((size_t)(p - (char*)d_ws) + PSZ <= ws_size) {  // room for a 4th partial?
    parts.p[2] = (float*)out;                        // d_out is scratch until out_tr
    parts.p[3] = (float*)alloc(PSZ);
    SPLIT = 4;
  }
  P4 none{};

  pos_kernel<<<1024, 256, 0, stream>>>(pos);
  convw_kernel<<<768, 256, 0, stream>>>(conv_w, convw);
  cf_tr_kernel<<<dim3(32, 8, 4), 256, 0, stream>>>(c_f, aconv);
  gemm_bt<EPI_BIAS_POS><<<dim3(6, 32), 256, 0, stream>>>(aconv, convw, conv_b, pos, x, 4096, 768, 256, none);

  for (int lyr = 0; lyr < 8; lyr++) {
    wconv_kernel<<<6912, 256, 0, stream>>>(qkv_w, out_w, m1w, m2w, wqkv, wout, wm1, wm2, lyr);
    if (lyr == 0) {
      ln_kernel<<<4096, 256, 0, stream>>>(x, ln1_w, ln1_b, y);
    } else if (SPLIT == 4) {
      redln_kernel<4, true><<<4096, 256, 0, stream>>>(parts, x, m2b + (lyr - 1) * 768,
                                                      ln1_w + lyr * 768, ln1_b + lyr * 768, x, y);
    } else {
      redln_kernel<2, true><<<4096, 256, 0, stream>>>(parts, x, m2b + (lyr - 1) * 768,
                                                      ln1_w + lyr * 768, ln1_b + lyr * 768, x, y);
    }
    gemm_bt<EPI_BF16><<<dim3(18, 32), 256, 0, stream>>>(y, wqkv, nullptr, nullptr, qkvb, 4096, 2304, 768, none);
    vtr_kernel<<<dim3(16, 48), 256, 0, stream>>>(qkvb, vT);
    attn_kernel<<<dim3(16, 48), 128, 0, stream>>>(qkvb, vT, ob);
    gemm_bt<EPI_BIAS_RES><<<dim3(6, 32), 256, 0, stream>>>(ob, wout, out_b + lyr * 768, x, x, 4096, 768, 768, none);
    ln_kernel<<<4096, 256, 0, stream>>>(x, ln2_w + lyr * 768, ln2_b + lyr * 768, y);
    gemm_bt<EPI_BIAS_GELU><<<dim3(24, 32), 256, 0, stream>>>(y, wm1, m1b + lyr * 3072, nullptr, hb, 4096, 3072, 768, none);
    // mlp2: split-K into fp32 partials (768 or 384 blocks -> latency hidden)
    gemm_bt<EPI_PART><<<dim3(6, 32, SPLIT), 256, 0, stream>>>(hb, wm2, nullptr, nullptr, nullptr, 4096, 768, 3072, parts);
  }
  // final combine (no LN needed; consumer is the output transpose)
  if (SPLIT == 4) {
    redln_kernel<4, false><<<4096, 256, 0, stream>>>(parts, x, m2b + 7 * 768, nullptr, nullptr, x, nullptr);
  } else {
    redln_kernel<2, false><<<4096, 256, 0, stream>>>(parts, x, m2b + 7 * 768, nullptr, nullptr, x, nullptr);
  }
  out_tr_kernel<<<dim3(24, 32, 4), 256, 0, stream>>>(x, out);
}

// Round 4
// 1709.031 us; speedup vs baseline: 1.3086x; 1.0552x over previous
//
#include <hip/hip_runtime.h>
#include <stdint.h>

typedef unsigned short u16;
typedef __attribute__((ext_vector_type(8))) short short8;
typedef __attribute__((ext_vector_type(4))) short s16x4;
typedef __attribute__((ext_vector_type(4))) float f32x4;

struct P4 { float* p[4]; };

#define DEV __device__ __forceinline__

DEV u16 f2bf(float f) {
  union { float f; uint32_t u; } c; c.f = f;
  uint32_t u = c.u;
  uint32_t r = u + 0x7fffu + ((u >> 16) & 1u);  // RNE
  return (u16)(r >> 16);
}

DEV void g2l16(const void* g, void* l) {
  __builtin_amdgcn_global_load_lds((__attribute__((address_space(1))) void*)(g),
                                   (__attribute__((address_space(3))) void*)(l),
                                   16, 0, 0);
}

// ---------------- positional embedding (PositionEmbeddingSine) ----------------
__global__ void pos_kernel(float* __restrict__ pos) {
  int n = blockIdx.x;
  float yv = (float)((n >> 5) + 1) / (32.0f + 1e-6f) * 6.283185307179586f;
  float xv = (float)((n & 31) + 1) / (32.0f + 1e-6f) * 6.283185307179586f;
#pragma unroll
  for (int i = 0; i < 3; i++) {
    int d = threadIdx.x + i * 256;
    int dd = (d < 384) ? d : d - 384;
    float base = (d < 384) ? yv : xv;
    float ex = (float)(dd & ~1) / 384.0f;     // 2*floor(dd/2)/384
    float arg = base / powf(10000.0f, ex);
    pos[(size_t)n * 768 + d] = (dd & 1) ? cosf(arg) : sinf(arg);
  }
}

// ---------------- conv_w fp32 [768][256] -> bf16 (already N x K) ----------------
__global__ void convw_kernel(const float* __restrict__ src, u16* __restrict__ dst) {
  int i = blockIdx.x * 256 + threadIdx.x;
  dst[i] = f2bf(src[i]);
}

// ---------------- 32x32 tile transpose fp32 -> bf16 ----------------
DEV void tile_tr32(const float* __restrict__ src, u16* __restrict__ dst,
                   int R, int C, int tr, int tc, float (*tile)[33]) {
  int tx = threadIdx.x & 31, ty = threadIdx.x >> 5;  // 32 x 8
#pragma unroll
  for (int i = 0; i < 32; i += 8)
    tile[ty + i][tx] = src[(size_t)(tr * 32 + ty + i) * C + tc * 32 + tx];
  __syncthreads();
#pragma unroll
  for (int i = 0; i < 32; i += 8)
    dst[(size_t)(tc * 32 + ty + i) * R + tr * 32 + tx] = f2bf(tile[tx][ty + i]);
}

// all four weights of one layer, transposed to [N][K] bf16, one launch
__global__ void wconv_kernel(const float* __restrict__ qkv_w, const float* __restrict__ out_w,
                             const float* __restrict__ m1w, const float* __restrict__ m2w,
                             u16* __restrict__ wqkv, u16* __restrict__ wout,
                             u16* __restrict__ wm1, u16* __restrict__ wm2, int layer) {
  __shared__ float tile[32][33];
  int tid = blockIdx.x;
  if (tid < 1728) {                                   // qkv_w: [768][2304] -> [2304][768]
    tile_tr32(qkv_w + (size_t)layer * 768 * 2304, wqkv, 768, 2304, tid / 72, tid % 72, tile);
  } else if (tid < 2304) {                            // out_w: [768][768]
    int t2 = tid - 1728;
    tile_tr32(out_w + (size_t)layer * 768 * 768, wout, 768, 768, t2 / 24, t2 % 24, tile);
  } else if (tid < 4608) {                            // mlp_w1: [768][3072] -> [3072][768]
    int t3 = tid - 2304;
    tile_tr32(m1w + (size_t)layer * 768 * 3072, wm1, 768, 3072, t3 / 96, t3 % 96, tile);
  } else {                                            // mlp_w2: [3072][768] -> [768][3072]
    int t4 = tid - 4608;
    tile_tr32(m2w + (size_t)layer * 3072 * 768, wm2, 3072, 768, t4 / 24, t4 % 24, tile);
  }
}

// c_f [B][256][1024] fp32 -> aconv [B][1024][256] bf16
__global__ void cf_tr_kernel(const float* __restrict__ c_f, u16* __restrict__ aconv) {
  __shared__ float tile[32][33];
  int b = blockIdx.z;
  tile_tr32(c_f + (size_t)b * 256 * 1024, aconv + (size_t)b * 1024 * 256,
            256, 1024, blockIdx.y, blockIdx.x, tile);
}

// x [B][1024][768] fp32 -> out [B][768][1024] fp32
__global__ void out_tr_kernel(const float* __restrict__ x, float* __restrict__ out) {
  __shared__ float tile[32][33];
  int b = blockIdx.z;
  const float* src = x + (size_t)b * 1024 * 768;
  float* dst = out + (size_t)b * 768 * 1024;
  int tr = blockIdx.y, tc = blockIdx.x;  // tr over n (32 tiles), tc over d (24 tiles)
  int tx = threadIdx.x & 31, ty = threadIdx.x >> 5;
#pragma unroll
  for (int i = 0; i < 32; i += 8)
    tile[ty + i][tx] = src[(size_t)(tr * 32 + ty + i) * 768 + tc * 32 + tx];
  __syncthreads();
#pragma unroll
  for (int i = 0; i < 32; i += 8)
    dst[(size_t)(tc * 32 + ty + i) * 1024 + tr * 32 + tx] = tile[tx][ty + i];
}

// ---------------- LayerNorm: fp32 in -> bf16 out ----------------
__global__ __launch_bounds__(256) void ln_kernel(const float* __restrict__ x,
                                                 const float* __restrict__ w,
                                                 const float* __restrict__ bsh,
                                                 u16* __restrict__ y) {
  int row = blockIdx.x, t = threadIdx.x;
  const float* xr = x + (size_t)row * 768;
  float v[3], s = 0.f, sq = 0.f;
#pragma unroll
  for (int i = 0; i < 3; i++) { v[i] = xr[t + i * 256]; s += v[i]; sq += v[i] * v[i]; }
#pragma unroll
  for (int off = 32; off; off >>= 1) { s += __shfl_xor(s, off); sq += __shfl_xor(sq, off); }
  __shared__ float ss[4], ssq[4];
  if ((t & 63) == 0) { ss[t >> 6] = s; ssq[t >> 6] = sq; }
  __syncthreads();
  s = ss[0] + ss[1] + ss[2] + ss[3];
  sq = ssq[0] + ssq[1] + ssq[2] + ssq[3];
  float mean = s * (1.0f / 768.0f);
  float var = sq * (1.0f / 768.0f) - mean * mean;
  float rs = rsqrtf(var + 1e-5f);
#pragma unroll
  for (int i = 0; i < 3; i++) {
    int c = t + i * 256;
    y[(size_t)row * 768 + c] = f2bf((v[i] - mean) * rs * w[c] + bsh[c]);
  }
}

// ---------------- fused split-K reduce (+ bias + residual) and LayerNorm ----------------
template <int S, bool DO_LN>
__global__ __launch_bounds__(256) void redln_kernel(P4 parts, const float* __restrict__ xin,
                                                    const float* __restrict__ bias,
                                                    const float* __restrict__ w,
                                                    const float* __restrict__ bsh,
                                                    float* __restrict__ xout,
                                                    u16* __restrict__ y) {
  int row = blockIdx.x, t = threadIdx.x;
  size_t base = (size_t)row * 768;
  float v[3], s = 0.f, sq = 0.f;
#pragma unroll
  for (int i = 0; i < 3; i++) {
    int c = t + i * 256;
    float acc = xin[base + c] + bias[c];
#pragma unroll
    for (int j = 0; j < S; j++) acc += parts.p[j][base + c];
    v[i] = acc;
    xout[base + c] = acc;
    s += acc; sq += acc * acc;
  }
  if constexpr (DO_LN) {
#pragma unroll
    for (int off = 32; off; off >>= 1) { s += __shfl_xor(s, off); sq += __shfl_xor(sq, off); }
    __shared__ float ss[4], ssq[4];
    if ((t & 63) == 0) { ss[t >> 6] = s; ssq[t >> 6] = sq; }
    __syncthreads();
    s = ss[0] + ss[1] + ss[2] + ss[3];
    sq = ssq[0] + ssq[1] + ssq[2] + ssq[3];
    float mean = s * (1.0f / 768.0f);
    float var = sq * (1.0f / 768.0f) - mean * mean;
    float rs = rsqrtf(var + 1e-5f);
#pragma unroll
    for (int i = 0; i < 3; i++) {
      int c = t + i * 256;
      y[base + c] = f2bf((v[i] - mean) * rs * w[c] + bsh[c]);
    }
  }
}

// ---------------- GEMM: C[M,N] = A[M,K](bf16) @ BT[N,K](bf16)^T, epilogues ----------------
constexpr int EPI_BF16 = 0, EPI_BIAS_RES = 1, EPI_BIAS_GELU = 2, EPI_BIAS_POS = 3, EPI_PART = 4;

template <int EPI>
__global__ __launch_bounds__(256, 2) void gemm_bt(
    const u16* __restrict__ A, const u16* __restrict__ BT,
    const float* __restrict__ bias, const float* __restrict__ res,
    void* __restrict__ Cout, int M, int N, int K, P4 parts) {
  __shared__ __align__(16) u16 As[128 * 32];
  __shared__ __align__(16) u16 Bs[128 * 32];
  const int t = threadIdx.x;
  const int w = t >> 6, l = t & 63, lr = l & 15, quad = l >> 4;
  const int bm = blockIdx.y * 128, bn = blockIdx.x * 128;
  const int wm = (w & 1) * 64, wn = (w >> 1) * 64;
  f32x4 acc[4][4];
#pragma unroll
  for (int i = 0; i < 4; i++)
#pragma unroll
    for (int j = 0; j < 4; j++) acc[i][j] = (f32x4){0.f, 0.f, 0.f, 0.f};
  const int c0 = t, c1 = 256 + t;
  const size_t a0 = (size_t)(bm + (c0 >> 2)) * K + (c0 & 3) * 8;
  const size_t a1 = (size_t)(bm + (c1 >> 2)) * K + (c1 & 3) * 8;
  const size_t b0 = (size_t)(bn + (c0 >> 2)) * K + (c0 & 3) * 8;
  const size_t b1 = (size_t)(bn + (c1 >> 2)) * K + (c1 & 3) * 8;
  const int kc = K / (int)gridDim.z;                // K-chunk for split-K (kc==K if z==1)
  const int kBeg = (int)blockIdx.z * kc;
  for (int k0 = kBeg; k0 < kBeg + kc; k0 += 32) {
    g2l16(A + a0 + k0, As + c0 * 8);
    g2l16(A + a1 + k0, As + c1 * 8);
    g2l16(BT + b0 + k0, Bs + c0 * 8);
    g2l16(BT + b1 + k0, Bs + c1 * 8);
    __syncthreads();
    short8 af[4], bf[4];
#pragma unroll
    for (int mi = 0; mi < 4; mi++) af[mi] = *(const short8*)(As + (wm + mi * 16 + lr) * 32 + quad * 8);
#pragma unroll
    for (int nj = 0; nj < 4; nj++) bf[nj] = *(const short8*)(Bs + (wn + nj * 16 + lr) * 32 + quad * 8);
#pragma unroll
    for (int mi = 0; mi < 4; mi++)
#pragma unroll
      for (int nj = 0; nj < 4; nj++)
        acc[mi][nj] = __builtin_amdgcn_mfma_f32_16x16x32_bf16(af[mi], bf[nj], acc[mi][nj], 0, 0, 0);
    __syncthreads();
  }
  float* Pc = (EPI == EPI_PART) ? parts.p[blockIdx.z] : nullptr;
#pragma unroll
  for (int mi = 0; mi < 4; mi++) {
    const int rowb = bm + wm + mi * 16 + quad * 4;
#pragma unroll
    for (int nj = 0; nj < 4; nj++) {
      const int gn = bn + wn + nj * 16 + lr;
#pragma unroll
      for (int r = 0; r < 4; r++) {
        const size_t idx = (size_t)(rowb + r) * N + gn;
        float v = acc[mi][nj][r];
        if constexpr (EPI == EPI_BF16) {
          ((u16*)Cout)[idx] = f2bf(v);
        } else if constexpr (EPI == EPI_BIAS_RES) {
          ((float*)Cout)[idx] = v + bias[gn] + res[idx];
        } else if constexpr (EPI == EPI_BIAS_GELU) {
          float xg = v + bias[gn];
          ((u16*)Cout)[idx] = f2bf(0.5f * xg * (1.0f + erff(xg * 0.70710678118f)));
        } else if constexpr (EPI == EPI_BIAS_POS) {  // conv epilogue, N==768
          ((float*)Cout)[idx] = v + bias[gn] + res[(size_t)((rowb + r) & 1023) * N + gn];
        } else {  // EPI_PART: fp32 partial, combined later by redln_kernel
          Pc[idx] = v;
        }
      }
    }
  }
}

// ---------------- V transpose: qkvb v-cols [4096][2304] -> vT [48][64][1024] ----------------
__global__ __launch_bounds__(256) void vtr_kernel(const u16* __restrict__ qkvb,
                                                  u16* __restrict__ vT) {
  __shared__ uint32_t tile[64][65];
  const int t = threadIdx.x;
  const int bh = blockIdx.y, b = bh / 12, h = bh % 12;
  const int tok0 = blockIdx.x * 64;
  {
    int trow = t >> 2, dc = (t & 3) * 16;
    const u16* src = qkvb + (size_t)(b * 1024 + tok0 + trow) * 2304 + 1536 + h * 64 + dc;
    short8 v0 = *(const short8*)src;
    short8 v1 = *(const short8*)(src + 8);
#pragma unroll
    for (int j = 0; j < 8; j++) {
      tile[trow][dc + j] = (uint32_t)(u16)v0[j];
      tile[trow][dc + 8 + j] = (uint32_t)(u16)v1[j];
    }
  }
  __syncthreads();
  {
    int d = t >> 2, tc = (t & 3) * 16;
    short8 o0, o1;
#pragma unroll
    for (int j = 0; j < 8; j++) {
      o0[j] = (short)(u16)tile[tc + j][d];
      o1[j] = (short)(u16)tile[tc + 8 + j][d];
    }
    u16* dst = vT + (size_t)(bh * 64 + d) * 1024 + tok0 + tc;
    *(short8*)dst = o0;
    *(short8*)(dst + 8) = o1;
  }
}

// ---------------- flash attention, S^T formulation, v2 ----------------
// Block = 256 threads (4 waves), each wave owns 16 q-rows (1 q-tile).
// K tile [ks][key][32] and V^T tile [ks][d][32] double-buffered in LDS via
// g2l16 with XOR-swizzled 16B columns (c' = c ^ ((row>>1)&3)): the global
// SOURCE lane address is pre-swizzled (g2l16 dest must stay linear) and the
// ds_read column applies the same xor -> 8-way bank conflict becomes 2-way.
// Prefetch: next tile's g2l16 issued before compute; single barrier per iter
// (the compiler's vmcnt(0) drain at __syncthreads is the only sync).
// Softmax unnormalized (|s*scale| << 88); P packed scalar f2bf (m240: hand
// cvt_pk is slower) and round-tripped through per-wave LDS into B-layout.
__global__ __launch_bounds__(256, 3) void attn_kernel(const u16* __restrict__ qkv,
                                                      const u16* __restrict__ vT,
                                                      u16* __restrict__ o) {
  __shared__ __align__(16) u16 Ks[2][2 * 64 * 32];   // [buf][ks][key][32]
  __shared__ __align__(16) u16 Vs[2][2 * 64 * 32];   // [buf][ks][d][32]
  __shared__ __align__(16) u16 Ps[4][16 * 72];       // per-wave P [qlocal][key], pad 72
  const int t = threadIdx.x;
  const int w = t >> 6, l = t & 63, lr = l & 15, quad = l >> 4;
  const int bh = blockIdx.y, b = bh / 12, h = bh % 12;
  const int qb = blockIdx.x * 64 + w * 16;           // 16 q-rows per wave
  const int swz = (lr >> 1) & 3;                     // read-side column xor

  // Q fragments (B-operand layout == [n=q][k=d])
  short8 aq[2];
#pragma unroll
  for (int ks = 0; ks < 2; ks++)
    aq[ks] = *(const short8*)(qkv + (size_t)(b * 1024 + qb + lr) * 2304 +
                              h * 64 + ks * 32 + quad * 8);

  const u16* kbase = qkv + (size_t)(b * 1024) * 2304 + 768 + h * 64;
  const u16* vbase = vT + (size_t)(bh * 64) * 1024;
  u16* Pw = Ps[w];

  f32x4 accO[4];   // [dj]: O^T[d=dj*16+quad*4+r][q=lr]
  float l_loc = 0.f;
#pragma unroll
  for (int dj = 0; dj < 4; dj++) accO[dj] = (f32x4){0.f, 0.f, 0.f, 0.f};

  // stage one 64-key tile into buffer `buf`; source column pre-swizzled
  auto stage = [&](int buf, int kb) {
#pragma unroll
    for (int pass = 0; pass < 2; pass++) {
      int u = pass * 256 + t;                  // 16B unit, 0..511
      int ks = u >> 8, row = (u >> 2) & 63, c4 = u & 3;
      int cs = c4 ^ ((row >> 1) & 3);          // pre-swizzled source column
      g2l16(kbase + (size_t)(kb + row) * 2304 + ks * 32 + cs * 8, Ks[buf] + (size_t)u * 8);
      g2l16(vbase + (size_t)row * 1024 + kb + ks * 32 + cs * 8, Vs[buf] + (size_t)u * 8);
    }
  };

  stage(0, 0);
  __syncthreads();
  int cur = 0;
  for (int kb = 0; kb < 1024; kb += 64) {
    if (kb + 64 < 1024) stage(cur ^ 1, kb + 64);   // prefetch next tile

    // ---- S^T = K @ Q^T ----
    f32x4 s[4];   // [nj keytile]
#pragma unroll
    for (int nj = 0; nj < 4; nj++) s[nj] = (f32x4){0.f, 0.f, 0.f, 0.f};
#pragma unroll
    for (int ks = 0; ks < 2; ks++)
#pragma unroll
      for (int nj = 0; nj < 4; nj++) {
        short8 ak = *(const short8*)(Ks[cur] + ks * 2048 + (nj * 16 + lr) * 32 + (quad ^ swz) * 8);
        s[nj] = __builtin_amdgcn_mfma_f32_16x16x32_bf16(ak, aq[ks], s[nj], 0, 0, 0);
      }

    // ---- unnormalized softmax; P[qlocal][key] packed b64 writes ----
    {
      const int rowoff = lr * 72;
#pragma unroll
      for (int nj = 0; nj < 4; nj++) {
        s16x4 pk;
#pragma unroll
        for (int r = 0; r < 4; r++) {
          float p = exp2f(s[nj][r] * 0.18033688011112042f);
          l_loc += p;
          pk[r] = (short)f2bf(p);
        }
        *(s16x4*)(Pw + rowoff + nj * 16 + quad * 4) = pk;
      }
    }

    // ---- O^T += V^T @ P^T ----
#pragma unroll
    for (int ks = 0; ks < 2; ks++) {
      short8 bp = *(const short8*)(Pw + lr * 72 + ks * 32 + quad * 8);
#pragma unroll
      for (int dj = 0; dj < 4; dj++) {
        short8 av = *(const short8*)(Vs[cur] + ks * 2048 + (dj * 16 + lr) * 32 + (quad ^ swz) * 8);
        accO[dj] = __builtin_amdgcn_mfma_f32_16x16x32_bf16(av, bp, accO[dj], 0, 0, 0);
      }
    }
    __syncthreads();   // drains prefetch (vmcnt 0) + protects K/V buffers
    cur ^= 1;
  }

  // l: reduce across the 4 quads (lanes lr, lr+16, lr+32, lr+48)
  l_loc += __shfl_xor(l_loc, 16);
  l_loc += __shfl_xor(l_loc, 32);
  // write O: token = qb + lr, d = h*64 + dj*16 + quad*4 + r (b64 stores)
  {
    float inv = 1.0f / l_loc;
    size_t grow = (size_t)(b * 1024 + qb + lr);
#pragma unroll
    for (int dj = 0; dj < 4; dj++) {
      s16x4 ov;
#pragma unroll
      for (int r = 0; r < 4; r++) ov[r] = (short)f2bf(accO[dj][r] * inv);
      *(s16x4*)(o + grow * 768 + h * 64 + dj * 16 + quad * 4) = ov;
    }
  }
}

// ---------------- driver ----------------
extern "C" void kernel_launch(void* const* d_in, const int* in_sizes, int n_in,
                              void* d_out, int out_size, void* d_ws, size_t ws_size,
                              hipStream_t stream) {
  (void)in_sizes; (void)n_in; (void)out_size;
  const float* c_f    = (const float*)d_in[0];
  const float* conv_w = (const float*)d_in[1];
  const float* conv_b = (const float*)d_in[2];
  const float* ln1_w  = (const float*)d_in[3];
  const float* ln1_b  = (const float*)d_in[4];
  const float* qkv_w  = (const float*)d_in[5];
  const float* out_w  = (const float*)d_in[6];
  const float* out_b  = (const float*)d_in[7];
  const float* ln2_w  = (const float*)d_in[8];
  const float* ln2_b  = (const float*)d_in[9];
  const float* m1w    = (const float*)d_in[10];
  const float* m1b    = (const float*)d_in[11];
  const float* m2w    = (const float*)d_in[12];
  const float* m2b    = (const float*)d_in[13];
  float* out = (float*)d_out;

  char* p = (char*)d_ws;
  auto alloc = [&](size_t bytes) { char* q = p; p += (bytes + 255) & ~(size_t)255; return q; };
  float* pos  = (float*)alloc(1024ull * 768 * 4);
  float* x    = (float*)alloc(4096ull * 768 * 4);
  u16* y      = (u16*)alloc(4096ull * 768 * 2);
  u16* qkvb   = (u16*)alloc(4096ull * 2304 * 2);
  u16* ob     = (u16*)alloc(4096ull * 768 * 2);
  u16* hb     = (u16*)alloc(4096ull * 3072 * 2);
  u16* aconv  = (u16*)alloc(4096ull * 256 * 2);
  u16* convw  = (u16*)alloc(768ull * 256 * 2);
  u16* wqkv   = (u16*)alloc(2304ull * 768 * 2);
  u16* wout   = (u16*)alloc(768ull * 768 * 2);
  u16* wm1    = (u16*)alloc(3072ull * 768 * 2);
  u16* wm2    = (u16*)alloc(768ull * 3072 * 2);
  // vT [48][64][1024] bf16 (6.3 MB) aliases hb (25 MB): hb dead during attn.
  u16* vT = hb;

  // ---- split-K partial buffers for mlp2 (each 4096*768*4 = 12.58 MB) ----
  const size_t PSZ = 4096ull * 768 * 4;
  P4 parts{};
  parts.p[0] = (float*)qkvb;
  parts.p[1] = (float*)((char*)qkvb + PSZ);
  int SPLIT = 2;
  if ((size_t)(p - (char*)d_ws) + PSZ <= ws_size) {  // room for a 4th partial?
    parts.p[2] = (float*)out;                        // d_out is scratch until out_tr
    parts.p[3] = (float*)alloc(PSZ);
    SPLIT = 4;
  }
  P4 none{};

  pos_kernel<<<1024, 256, 0, stream>>>(pos);
  convw_kernel<<<768, 256, 0, stream>>>(conv_w, convw);
  cf_tr_kernel<<<dim3(32, 8, 4), 256, 0, stream>>>(c_f, aconv);
  gemm_bt<EPI_BIAS_POS><<<dim3(6, 32), 256, 0, stream>>>(aconv, convw, conv_b, pos, x, 4096, 768, 256, none);

  for (int lyr = 0; lyr < 8; lyr++) {
    wconv_kernel<<<6912, 256, 0, stream>>>(qkv_w, out_w, m1w, m2w, wqkv, wout, wm1, wm2, lyr);
    if (lyr == 0) {
      ln_kernel<<<4096, 256, 0, stream>>>(x, ln1_w, ln1_b, y);
    } else if (SPLIT == 4) {
      redln_kernel<4, true><<<4096, 256, 0, stream>>>(parts, x, m2b + (lyr - 1) * 768,
                                                      ln1_w + lyr * 768, ln1_b + lyr * 768, x, y);
    } else {
      redln_kernel<2, true><<<4096, 256, 0, stream>>>(parts, x, m2b + (lyr - 1) * 768,
                                                      ln1_w + lyr * 768, ln1_b + lyr * 768, x, y);
    }
    gemm_bt<EPI_BF16><<<dim3(18, 32), 256, 0, stream>>>(y, wqkv, nullptr, nullptr, qkvb, 4096, 2304, 768, none);
    vtr_kernel<<<dim3(16, 48), 256, 0, stream>>>(qkvb, vT);
    attn_kernel<<<dim3(16, 48), 256, 0, stream>>>(qkvb, vT, ob);
    gemm_bt<EPI_BIAS_RES><<<dim3(6, 32), 256, 0, stream>>>(ob, wout, out_b + lyr * 768, x, x, 4096, 768, 768, none);
    ln_kernel<<<4096, 256, 0, stream>>>(x, ln2_w + lyr * 768, ln2_b + lyr * 768, y);
    gemm_bt<EPI_BIAS_GELU><<<dim3(24, 32), 256, 0, stream>>>(y, wm1, m1b + lyr * 3072, nullptr, hb, 4096, 3072, 768, none);
    // mlp2: split-K into fp32 partials (768 or 384 blocks -> latency hidden)
    gemm_bt<EPI_PART><<<dim3(6, 32, SPLIT), 256, 0, stream>>>(hb, wm2, nullptr, nullptr, nullptr, 4096, 768, 3072, parts);
  }
  // final combine (no LN needed; consumer is the output transpose)
  if (SPLIT == 4) {
    redln_kernel<4, false><<<4096, 256, 0, stream>>>(parts, x, m2b + 7 * 768, nullptr, nullptr, x, nullptr);
  } else {
    redln_kernel<2, false><<<4096, 256, 0, stream>>>(parts, x, m2b + 7 * 768, nullptr, nullptr, x, nullptr);
  }
  out_tr_kernel<<<dim3(24, 32, 4), 256, 0, stream>>>(x, out);
}